// Round 5
// baseline (332.480 us; speedup 1.0000x reference)
//
#include <hip/hip_runtime.h>

#define B 4
#define N 2048
#define V 12
#define C 50
#define P 16384      // 128*128 = 2^14
#define PH (P/2)     // 8192 pixel-pairs per image
#define PSTRIDE 56   // floats per pool entry: 50 exps + sum + pad (224 B)

typedef unsigned long long u64;

// ---------------------------------------------------------------------------
// Fused single streaming pass. 2 pixels/thread via float2 (coalesced).
// Logits stay in registers; mask-passing pixels (~7%) compact their
// exp-vector into pool[slot] and scatter key64 = ((argmax*P+pix)<<20)|slot
// via 64-bit atomicMax. (argmax,pix) unique per candidate => max semantics
// identical to the reference's .at[].max(kkey); low bits deliver the
// winner's payload slot to k3 for free. No second read of pred, ever.
// ---------------------------------------------------------------------------
__global__ __launch_bounds__(256) void k1_fused(
    const float2* __restrict__ predv,    // (B*V, C, PH)
    const int2*  __restrict__ p2pv,      // (B*V, PH)
    const int*   __restrict__ parts_nb,  // (B,)
    u64*         __restrict__ winner,    // (B*V*N), zero-init
    unsigned int* __restrict__ counter,  // zero-init
    float*       __restrict__ pool) {    // (B*V*P, PSTRIDE) worst case
  int t = blockIdx.x * 256 + threadIdx.x;   // t < B*V*PH (grid exact)
  int q  = t & (PH - 1);
  int bv = t >> 13;
  int b  = bv / V;

  size_t base = (size_t)bv * C * PH + q;
  float l0[C], l1[C];
  float m0, m1;
  int a0 = 0, a1 = 0;
  {
    float2 x = predv[base];
    l0[0] = x.x; l1[0] = x.y; m0 = x.x; m1 = x.y;
  }
  #pragma unroll
  for (int c = 1; c < C; ++c) {
    float2 y = predv[base + (size_t)c * PH];
    l0[c] = y.x; l1[c] = y.y;
    if (y.x > m0) { m0 = y.x; a0 = c; }
    if (y.y > m1) { m1 = y.y; a1 = c; }
  }

  int2 pt = p2pv[(size_t)bv * PH + q];
  int pn = parts_nb[b];
  int p0 = q * 2;

  bool v0 = (pt.x != -1) && (a0 >= 1) && (a0 <= pn);
  bool v1 = (pt.y != -1) && (a1 >= 1) && (a1 <= pn);

  if (v0) {
    unsigned int slot = atomicAdd(counter, 1u);       // wave-aggregated by LLVM
    u64 key = ((u64)(a0 * P + p0) << 20) | (u64)slot; // slot < 2^20 always
    atomicMax(&winner[bv * N + pt.x], key);
    float s = 0.f;
    float* dst = pool + (size_t)slot * PSTRIDE;
    #pragma unroll
    for (int c = 0; c < C; ++c) { float e = __expf(l0[c]); dst[c] = e; s += e; }
    dst[C] = s;
  }
  if (v1) {
    unsigned int slot = atomicAdd(counter, 1u);
    u64 key = ((u64)(a1 * P + p0 + 1) << 20) | (u64)slot;
    atomicMax(&winner[bv * N + pt.y], key);
    float s = 0.f;
    float* dst = pool + (size_t)slot * PSTRIDE;
    #pragma unroll
    for (int c = 0; c < C; ++c) { float e = __expf(l1[c]); dst[c] = e; s += e; }
    dst[C] = s;
  }
}

// ---------------------------------------------------------------------------
// Reduce: one wave per (b,n). Winner key's low 20 bits index the pool;
// lanes 0..49 read the 224 B entry contiguously (coalesced). Average valid
// views with vw/sumexp weights; never-hit points output 0 (cnt=0 -> /1).
// ---------------------------------------------------------------------------
__global__ __launch_bounds__(256) void k3_reduce(
    const u64*  __restrict__ winner,    // (B*V*N)
    const float* __restrict__ pool,
    const float* __restrict__ vw,       // (B*V,)
    float*       __restrict__ out) {    // (B, C, N)
  int wid  = blockIdx.x * 4 + (threadIdx.x >> 6);
  int lane = threadIdx.x & 63;
  int b = wid >> 11;                    // N = 2048
  int n = wid & (N - 1);

  float acc = 0.f;
  int cnt = 0;
  #pragma unroll
  for (int v = 0; v < V; ++v) {
    u64 key = winner[(b * V + v) * N + n];
    bool valid = key != 0ull;           // valid keys have argmax>=1 => key >= P<<20
    unsigned int slot = (unsigned int)(key & 0xFFFFFu);
    const float* src = pool + (size_t)slot * PSTRIDE;
    float e = (valid && lane < C) ? src[lane] : 0.f;
    float s = valid ? src[C] : 1.f;
    float f = valid ? (vw[b * V + v] / s) : 0.f;
    cnt += valid ? 1 : 0;
    acc += e * f;
  }
  if (lane < C)
    out[((size_t)b * C + lane) * N + n] = acc / (float)(cnt > 0 ? cnt : 1);
}

extern "C" void kernel_launch(void* const* d_in, const int* in_sizes, int n_in,
                              void* d_out, int out_size, void* d_ws, size_t ws_size,
                              hipStream_t stream) {
  const float* pred  = (const float*)d_in[1];
  const int*   p2p   = (const int*)d_in[2];
  const float* vw    = (const float*)d_in[3];
  const int*   parts = (const int*)d_in[4];
  float* out = (float*)d_out;

  char* ws = (char*)d_ws;
  unsigned int* counter = (unsigned int*)ws;                 // 256 B reserved
  u64*   winner = (u64*)(ws + 256);                          // 768 KiB
  float* pool   = (float*)(ws + 256 + (size_t)B * V * N * sizeof(u64)); // <=176 MiB

  // zero counter + winner in one fill (769 KB)
  hipMemsetAsync(ws, 0, 256 + (size_t)B * V * N * sizeof(u64), stream);

  int nthreads = B * V * PH;                                 // 393216
  k1_fused<<<nthreads / 256, 256, 0, stream>>>(
      (const float2*)pred, (const int2*)p2p, parts, winner, counter, pool);

  k3_reduce<<<(B * N) / 4, 256, 0, stream>>>(winner, pool, vw, out);
}

// Round 6
// 256.892 us; speedup vs baseline: 1.2942x; 1.2942x over previous
//
#include <hip/hip_runtime.h>

#define B 4
#define N 2048
#define V 12
#define C 50
#define P 16384      // 128*128 = 2^14
#define PSTRIDE 56   // floats per pool entry: 50 exps + sum + pad (224 B, 16B-aligned)

// ---------------------------------------------------------------------------
// Fused single streaming pass. ONE pixel per thread: the 50 logits live in
// registers (no spill at <=256 VGPR budget via __launch_bounds__(256,2)).
// Mask-passing pixels (~7%) write their exp-vector + sum to pool[bv*P + p]
// (deterministic slot -- no compaction counter, no contended atomics) and
// scatter the reference's exact key = argmax*P + p via 32-bit atomicMax.
// pred is read exactly once, fully coalesced. No second pass exists.
// ---------------------------------------------------------------------------
__global__ __launch_bounds__(256, 2) void k1_fused(
    const float* __restrict__ pred,      // (B*V, C, P)
    const int*   __restrict__ p2p,       // (B*V, P)
    const int*   __restrict__ parts_nb,  // (B,)
    int*         __restrict__ winner,    // (B*V*N), init -1
    float*       __restrict__ pool) {    // (B*V*P, PSTRIDE)
  int t = blockIdx.x * 256 + threadIdx.x;   // grid exact: B*V*P threads
  int p  = t & (P - 1);
  int bv = t >> 14;
  int b  = bv / V;

  const float* pp = pred + (size_t)bv * C * P + p;
  float l[C];
  #pragma unroll
  for (int c = 0; c < C; ++c) l[c] = pp[(size_t)c * P];   // 50 independent loads

  float m = l[0];
  int   a = 0;
  #pragma unroll
  for (int c = 1; c < C; ++c) if (l[c] > m) { m = l[c]; a = c; }

  int pt = p2p[(size_t)bv * P + p];
  int pn = parts_nb[b];
  if (pt != -1 && a >= 1 && a <= pn) {
    float s = 0.f;
    float* dst = pool + (size_t)(bv * P + p) * PSTRIDE;
    #pragma unroll
    for (int c = 0; c < C; ++c) { float e = __expf(l[c]); dst[c] = e; s += e; }
    dst[C] = s;
    atomicMax(&winner[bv * N + pt], a * P + p);   // reference's exact key
  }
}

// ---------------------------------------------------------------------------
// Reduce: one wave per (b,n). key & (P-1) is the winning pixel -> pool slot.
// Lanes 0..49 read the 224 B entry contiguously (L2/L3-hot). Average valid
// views with vw/sumexp weights; cnt=0 -> divide by 1 (output 0).
// ---------------------------------------------------------------------------
__global__ __launch_bounds__(256) void k3_reduce(
    const int*   __restrict__ winner,   // (B*V*N)
    const float* __restrict__ pool,     // (B*V*P, PSTRIDE)
    const float* __restrict__ vw,       // (B*V,)
    float*       __restrict__ out) {    // (B, C, N)
  int wid  = blockIdx.x * 4 + (threadIdx.x >> 6);
  int lane = threadIdx.x & 63;
  int b = wid >> 11;                    // N = 2048
  int n = wid & (N - 1);

  float acc = 0.f;
  int cnt = 0;
  #pragma unroll
  for (int v = 0; v < V; ++v) {
    int bv  = b * V + v;
    int key = winner[bv * N + n];       // wave-uniform -> scalar broadcast
    bool valid = key >= 0;
    int wp = key & (P - 1);
    const float* src = pool + (size_t)(bv * P + wp) * PSTRIDE;
    float e = (valid && lane < C) ? src[lane] : 0.f;
    float s = valid ? src[C] : 1.f;
    float f = valid ? (vw[bv] / s) : 0.f;
    cnt += valid ? 1 : 0;
    acc += e * f;
  }
  if (lane < C)
    out[((size_t)b * C + lane) * N + n] = acc / (float)(cnt > 0 ? cnt : 1);
}

extern "C" void kernel_launch(void* const* d_in, const int* in_sizes, int n_in,
                              void* d_out, int out_size, void* d_ws, size_t ws_size,
                              hipStream_t stream) {
  const float* pred  = (const float*)d_in[1];
  const int*   p2p   = (const int*)d_in[2];
  const float* vw    = (const float*)d_in[3];
  const int*   parts = (const int*)d_in[4];
  float* out = (float*)d_out;

  char* ws = (char*)d_ws;
  int*   winner = (int*)ws;                                  // 384 KiB
  float* pool   = (float*)(ws + (size_t)B * V * N * sizeof(int) + 128); // 176 MiB max

  hipMemsetAsync(winner, 0xFF, (size_t)B * V * N * sizeof(int), stream); // -1 fill

  int nthreads = B * V * P;                                  // 786432
  k1_fused<<<nthreads / 256, 256, 0, stream>>>(
      pred, p2p, parts, winner, pool);

  k3_reduce<<<(B * N) / 4, 256, 0, stream>>>(winner, pool, vw, out);
}